// Round 1
// baseline (438.056 us; speedup 1.0000x reference)
//
#include <hip/hip_runtime.h>
#include <hip/hip_bf16.h>
#include <cstdint>
#include <cstddef>

#define EPS 1e-8f
#define H_T 2.0794415416798357f /* ln(8) */
#define NUM_MARKED 4194304.0f   /* B*K: is_event is exactly one-hot over T */

typedef __attribute__((ext_vector_type(8))) short bf16x8;
typedef __attribute__((ext_vector_type(4))) float f32x4;

__device__ __forceinline__ unsigned short f2bf(float f) {
    union { float f; unsigned u; } v; v.f = f;
    unsigned r = v.u + 0x7fffu + ((v.u >> 16) & 1u);
    return (unsigned short)(r >> 16);
}

__device__ __forceinline__ void gl_lds16(const void* g, void* l) {
    __builtin_amdgcn_global_load_lds((const __attribute__((address_space(1))) unsigned int*)g,
                                     (__attribute__((address_space(3))) unsigned int*)l, 16, 0, 0);
}

// ---------------- fused prep ----------------
// grid: [0,1536) feat conv | [1536,4608) W1^T | [4608,8704) W2^T |
//       [8704,12800) compress is_event/ratio/is_cens -> packed(u8) + ratio_sel(f32)
// The compress segment is a pure streaming pass: 272 MB read at 16 B/lane
// coalescing, 20 MB written. It removes 16 of 17 epilogue loads per (b,k)
// from gemm_loss (is_event is one-hot over T: only t_event and
// ratio[b,t_event,k] are ever consumed).
__global__ __launch_bounds__(256) void prep_kernel(const float* __restrict__ features,
                                                   const float* __restrict__ W1,
                                                   const float* __restrict__ W2,
                                                   const int* __restrict__ is_event,
                                                   const int* __restrict__ is_cens,
                                                   const float* __restrict__ ratio,
                                                   unsigned short* __restrict__ featbf,
                                                   unsigned short* __restrict__ W1T,
                                                   unsigned short* __restrict__ W2T,
                                                   unsigned char* __restrict__ packed,
                                                   float* __restrict__ ratio_sel,
                                                   float* __restrict__ accum) {
    int bid = blockIdx.x;
    int tid = threadIdx.x;
    if (bid < 1536) {
        if (bid == 0 && tid < 8) accum[tid] = 0.0f;
        int i = bid * 256 + tid;
        featbf[i] = f2bf(features[i]);
        return;
    }
    if (bid >= 8704) {
        // ---- compress: 4 consecutive (b,k) pairs per thread ----
        const int NK = 8192;
        int gid = (bid - 8704) * 256 + tid;        // [0, 1048576)
        int b = gid >> 11;                         // 2048 groups of 4 per b-row
        int k0 = (gid & 2047) * 4;
        size_t base = (size_t)b * 8 * NK + k0;

        int   tev[4]  = {0, 0, 0, 0};
        float rsel[4] = {0.f, 0.f, 0.f, 0.f};
#pragma unroll
        for (int t = 0; t < 8; t++) {
            int4   ev4 = *(const int4*)(is_event + base + (size_t)t * NK);
            float4 rt4 = *(const float4*)(ratio + base + (size_t)t * NK);
            int   vv[4] = {ev4.x, ev4.y, ev4.z, ev4.w};
            float rr[4] = {rt4.x, rt4.y, rt4.z, rt4.w};
#pragma unroll
            for (int j = 0; j < 4; j++) {
                bool e = vv[j] != 0;
                tev[j]  = e ? t : tev[j];
                rsel[j] = e ? rr[j] : rsel[j];
            }
        }
        int4 c4 = *(const int4*)(is_cens + (size_t)b * NK + k0);
        int cc[4] = {c4.x, c4.y, c4.z, c4.w};

        uchar4 pk4;
        pk4.x = (unsigned char)(tev[0] | ((cc[0] != 0) << 3));
        pk4.y = (unsigned char)(tev[1] | ((cc[1] != 0) << 3));
        pk4.z = (unsigned char)(tev[2] | ((cc[2] != 0) << 3));
        pk4.w = (unsigned char)(tev[3] | ((cc[3] != 0) << 3));
        *(uchar4*)(packed + (size_t)gid * 4) = pk4;
        float4 rs4; rs4.x = rsel[0]; rs4.y = rsel[1]; rs4.z = rsel[2]; rs4.w = rsel[3];
        *(float4*)(ratio_sel + (size_t)gid * 4) = rs4;
        return;
    }
    // ---- W transposes (f32 -> bf16) ----
    const float* in; unsigned short* out; int R, C, bx, by;
    if (bid < 4608) {
        int b = bid - 1536; in = W1; out = W1T; R = 768; C = 4096;
        bx = b & 127; by = b >> 7;     // 128 x-tiles
    } else {
        int b = bid - 4608; in = W2; out = W2T; R = 512; C = 8192;
        bx = b & 255; by = b >> 8;     // 256 x-tiles
    }
    __shared__ float tile[32][33];
    int c0 = bx * 32, r0 = by * 32;
    int tx = tid & 31, ty = tid >> 5;  // ty in [0,8)
#pragma unroll
    for (int i = 0; i < 4; i++) {
        int r = ty + i * 8;
        tile[r][tx] = in[(size_t)(r0 + r) * C + c0 + tx];
    }
    __syncthreads();
#pragma unroll
    for (int i = 0; i < 4; i++) {
        int cc = ty + i * 8;
        out[(size_t)(c0 + cc) * R + r0 + tx] = f2bf(tile[tx][cc]);
    }
}

// ---------------- GEMM1: C(MxN) = A(MxK) * BT(NxK)^T + bias, f32 out ----------------
// 64x64 tile, 256 threads, 2x2 waves, 16x16x32 bf16 MFMA, BK=32
__global__ __launch_bounds__(256) void gemm_bias(const unsigned short* __restrict__ A,
                                                 const unsigned short* __restrict__ BT,
                                                 const float* __restrict__ bias,
                                                 float* __restrict__ C,
                                                 int M, int N, int K) {
    __shared__ unsigned short lA[64 * 40];
    __shared__ unsigned short lB[64 * 40];
    int m0 = blockIdx.x * 64, n0 = blockIdx.y * 64;
    int tid = threadIdx.x;
    int lane = tid & 63, wave = tid >> 6;
    int wm = wave >> 1, wn = wave & 1;
    int r = lane & 15, q = lane >> 4;

    f32x4 acc[2][2];
#pragma unroll
    for (int i = 0; i < 2; i++)
#pragma unroll
        for (int j = 0; j < 2; j++) acc[i][j] = (f32x4){0.f, 0.f, 0.f, 0.f};

    int ldrow = tid >> 2, ldc = (tid & 3) * 8;

    for (int kk = 0; kk < K; kk += 32) {
        uint4 av = *(const uint4*)(A + (size_t)(m0 + ldrow) * K + kk + ldc);
        uint4 bv = *(const uint4*)(BT + (size_t)(n0 + ldrow) * K + kk + ldc);
        __syncthreads();
        *(uint4*)(&lA[ldrow * 40 + ldc]) = av;
        *(uint4*)(&lB[ldrow * 40 + ldc]) = bv;
        __syncthreads();

        bf16x8 a0 = *(const bf16x8*)(&lA[(wm * 32 + r) * 40 + q * 8]);
        bf16x8 a1 = *(const bf16x8*)(&lA[(wm * 32 + 16 + r) * 40 + q * 8]);
        bf16x8 b0 = *(const bf16x8*)(&lB[(wn * 32 + r) * 40 + q * 8]);
        bf16x8 b1 = *(const bf16x8*)(&lB[(wn * 32 + 16 + r) * 40 + q * 8]);
        acc[0][0] = __builtin_amdgcn_mfma_f32_16x16x32_bf16(a0, b0, acc[0][0], 0, 0, 0);
        acc[0][1] = __builtin_amdgcn_mfma_f32_16x16x32_bf16(a0, b1, acc[0][1], 0, 0, 0);
        acc[1][0] = __builtin_amdgcn_mfma_f32_16x16x32_bf16(a1, b0, acc[1][0], 0, 0, 0);
        acc[1][1] = __builtin_amdgcn_mfma_f32_16x16x32_bf16(a1, b1, acc[1][1], 0, 0, 0);
    }

#pragma unroll
    for (int i = 0; i < 2; i++)
#pragma unroll
        for (int j = 0; j < 2; j++)
#pragma unroll
            for (int reg = 0; reg < 4; reg++) {
                int row = m0 + wm * 32 + i * 16 + q * 4 + reg;
                int col = n0 + wn * 32 + j * 16 + r;
                C[(size_t)row * N + col] = acc[i][j][reg] + bias[col];
            }
}

// ---------------- RMSNorm: x(4096x512) f32 -> xn(4096x512) bf16 ----------------
__global__ __launch_bounds__(256) void rms_kernel(const float* __restrict__ x,
                                                  const float* __restrict__ norm_w,
                                                  unsigned short* __restrict__ xn) {
    int m = blockIdx.x;
    int tid = threadIdx.x;
    const float* row = x + (size_t)m * 512;
    float v0 = row[tid];
    float v1 = row[tid + 256];
    float ss = v0 * v0 + v1 * v1;
#pragma unroll
    for (int o = 32; o > 0; o >>= 1) ss += __shfl_down(ss, o);
    __shared__ float rs[4];
    __shared__ float scale_sh;
    int lane = tid & 63, wave = tid >> 6;
    if (lane == 0) rs[wave] = ss;
    __syncthreads();
    if (tid == 0) {
        float tot = rs[0] + rs[1] + rs[2] + rs[3];
        scale_sh = 1.0f / sqrtf(tot * (1.0f / 512.0f) + 1e-6f);
    }
    __syncthreads();
    float s = scale_sh;
    xn[(size_t)m * 512 + tid] = f2bf(v0 * s * norm_w[tid]);
    xn[(size_t)m * 512 + tid + 256] = f2bf(v1 * s * norm_w[tid + 256]);
}

// ---------------- GEMM2 + softmax/cumsum/loss, fused (m97-style) ----------------
// M=4096, N=8192, K=512. BM=BN=128, BK=64, 256 threads = 4 waves (2x2).
// Epilogue now reads only packed(u8) + ratio_sel(f32) per (b,k) — 2 loads
// instead of 17 (compress prepass exploits one-hot is_event). Count term
// is the structural constant B*K (exactly one event per (b,k)).
__global__ __launch_bounds__(256) void gemm_loss(const unsigned short* __restrict__ A,
                                                 const unsigned short* __restrict__ BT,
                                                 const unsigned char* __restrict__ packed,
                                                 const float* __restrict__ ratio_sel,
                                                 float* __restrict__ accum) {
    const int K = 512, NK = 8192;
    __shared__ unsigned short lA[8 * 128 * 8];   // 16 KB: [kc][m][8]
    __shared__ unsigned short lB[8 * 128 * 8];   // 16 KB: [kc][n][8]
    __shared__ float lg[32 * 132];               // logits chunk, stride 132 (2-way max)
    __shared__ float rsum[4];

    int m0 = blockIdx.x * 128, n0 = blockIdx.y * 128;
    int tid = threadIdx.x;
    int lane = tid & 63, wave = tid >> 6;
    int wm = wave >> 1, wn = wave & 1;
    int r = lane & 15, q = lane >> 4;

    f32x4 acc[4][4];
#pragma unroll
    for (int i = 0; i < 4; i++)
#pragma unroll
        for (int j = 0; j < 4; j++) acc[i][j] = (f32x4){0.f, 0.f, 0.f, 0.f};

    for (int kk = 0; kk < K; kk += 64) {
        __syncthreads();   // previous iter's ds_reads complete
#pragma unroll
        for (int inst = 0; inst < 4; inst++) {
            int e = inst * 256 + tid;          // 0..1023
            int kc = e >> 7, m = e & 127;
            gl_lds16(A + (size_t)(m0 + m) * K + kk + kc * 8, (char*)lA + e * 16);
        }
#pragma unroll
        for (int inst = 0; inst < 4; inst++) {
            int e = inst * 256 + tid;
            int kc = e >> 7, n = e & 127;
            gl_lds16(BT + (size_t)(n0 + n) * K + kk + kc * 8, (char*)lB + e * 16);
        }
        __syncthreads();   // drains vmcnt -> staged data visible

#pragma unroll
        for (int ks = 0; ks < 2; ks++) {
            bf16x8 a[4], b[4];
#pragma unroll
            for (int i = 0; i < 4; i++)
                a[i] = *(const bf16x8*)((const char*)lA + (size_t)((ks * 4 + q) * 128 + wm * 64 + i * 16 + r) * 16);
#pragma unroll
            for (int j = 0; j < 4; j++)
                b[j] = *(const bf16x8*)((const char*)lB + (size_t)((ks * 4 + q) * 128 + wn * 64 + j * 16 + r) * 16);
#pragma unroll
            for (int i = 0; i < 4; i++)
#pragma unroll
                for (int j = 0; j < 4; j++)
                    acc[i][j] = __builtin_amdgcn_mfma_f32_16x16x32_bf16(a[i], b[j], acc[i][j], 0, 0, 0);
        }
    }

    // ---- epilogue: 4 chunks of 32 rows (4 b's x 8 t's) x 128 cols ----
    float lsum = 0.0f;
#pragma unroll
    for (int c = 0; c < 4; c++) {
        __syncthreads();   // previous chunk fully read (and k-loop ds_reads done)
        if (wm == (c >> 1)) {
#pragma unroll
            for (int di = 0; di < 2; di++)
#pragma unroll
                for (int j = 0; j < 4; j++)
#pragma unroll
                    for (int reg = 0; reg < 4; reg++) {
                        int lrow = di * 16 + q * 4 + reg;
                        int col = wn * 64 + j * 16 + r;
                        lg[lrow * 132 + col] = acc[(c & 1) * 2 + di][j][reg];
                    }
        }
        __syncthreads();

#pragma unroll
        for (int p = 0; p < 2; p++) {
            int idx = tid + p * 256;            // 512 (b,k) pairs per chunk
            int bl = idx >> 7, kl = idx & 127;  // bl in [0,4)
            int b = (m0 >> 3) + 4 * c + bl;
            int k = n0 + kl;
            size_t pidx = (size_t)b * NK + k;

            int pk = packed[pidx];
            float rsel = ratio_sel[pidx];
            int tev = pk & 7;
            bool cen = (pk & 8) != 0;

            float L[8];
#pragma unroll
            for (int t = 0; t < 8; t++) L[t] = lg[(bl * 8 + t) * 132 + kl];
            float mx = L[0];
#pragma unroll
            for (int t = 1; t < 8; t++) mx = fmaxf(mx, L[t]);
            float e[8], s = 0.0f;
#pragma unroll
            for (int t = 0; t < 8; t++) { e[t] = __expf(L[t] - mx); s += e[t]; }
            float inv = 1.0f / s;

            float cum = 0.0f, pte = 0.0f, ite = 0.0f;
#pragma unroll
            for (int t = 0; t < 8; t++) {
                float pt = e[t] * inv;
                float integ = 1.0f - cum;
                cum += pt;
                bool hit = (t == tev);
                pte = hit ? pt : pte;
                ite = hit ? integ : ite;
            }
            float ps  = fminf(fmaxf(pte, EPS), 1.0f - EPS);
            float is0 = fminf(fmaxf(ite, EPS), 1.0f - EPS);
            float isc = fminf(fmaxf(is0 - rsel * ps, EPS), 1.0f - EPS);
            float val = cen ? isc : ps;
            lsum += logf(val);
        }
    }

    // block reduction
#pragma unroll
    for (int o = 32; o > 0; o >>= 1) lsum += __shfl_down(lsum, o);
    if (lane == 0) rsum[wave] = lsum;
    __syncthreads();
    if (tid == 0) {
        atomicAdd(&accum[0], rsum[0] + rsum[1] + rsum[2] + rsum[3]);
    }
}

__global__ void finalize_kernel(const float* __restrict__ accum, float* __restrict__ out) {
    out[0] = -accum[0] / (NUM_MARKED * H_T);
}

extern "C" void kernel_launch(void* const* d_in, const int* in_sizes, int n_in,
                              void* d_out, int out_size, void* d_ws, size_t ws_size,
                              hipStream_t stream) {
    const float* features = (const float*)d_in[0]; // 512x768
    const float* W1       = (const float*)d_in[1]; // 768x4096
    const float* b1       = (const float*)d_in[2]; // 4096
    const float* norm_w   = (const float*)d_in[3]; // 512
    const float* W2       = (const float*)d_in[4]; // 512x8192
    /* b2 (d_in[5]) is softmax(axis=1)-invariant: skipped */
    const int* is_event   = (const int*)d_in[6];   // 512x8x8192 (bool as i32)
    const int* is_cens    = (const int*)d_in[7];   // 512x8192  (bool as i32)
    const float* ratio    = (const float*)d_in[8]; // 512x8x8192
    float* out = (float*)d_out;

    char* ws = (char*)d_ws;
    size_t off = 0;
    auto alloc = [&](size_t bytes) { void* p = ws + off; off = (off + bytes + 255) & ~(size_t)255; return p; };
    unsigned short* W1T    = (unsigned short*)alloc((size_t)4096 * 768 * 2);
    unsigned short* W2T    = (unsigned short*)alloc((size_t)8192 * 512 * 2);
    unsigned short* featbf = (unsigned short*)alloc((size_t)512 * 768 * 2);
    float*          xbuf   = (float*)alloc((size_t)512 * 4096 * 4);
    unsigned short* xn     = (unsigned short*)alloc((size_t)4096 * 512 * 2);
    unsigned char*  packed = (unsigned char*)alloc((size_t)512 * 8192);
    float*          rsel   = (float*)alloc((size_t)512 * 8192 * 4);
    float*          accum  = (float*)alloc(64);

    prep_kernel<<<12800, 256, 0, stream>>>(features, W1, W2, is_event, is_cens, ratio,
                                           featbf, W1T, W2T, packed, rsel, accum);
    gemm_bias<<<dim3(512 / 64, 4096 / 64), 256, 0, stream>>>(featbf, W1T, b1, xbuf, 512, 4096, 768);
    rms_kernel<<<4096, 256, 0, stream>>>(xbuf, norm_w, xn);
    gemm_loss<<<dim3(4096 / 128, 8192 / 128), 256, 0, stream>>>(xn, W2T, packed, rsel, accum);
    finalize_kernel<<<1, 1, 0, stream>>>(accum, out);
}

// Round 2
// 418.450 us; speedup vs baseline: 1.0469x; 1.0469x over previous
//
#include <hip/hip_runtime.h>
#include <hip/hip_bf16.h>
#include <cstdint>
#include <cstddef>

#define EPS 1e-8f
#define H_T 2.0794415416798357f /* ln(8) */
#define NUM_MARKED 4194304.0f   /* B*K: is_event is exactly one-hot over T */

typedef __attribute__((ext_vector_type(8))) short bf16x8;
typedef __attribute__((ext_vector_type(4))) float f32x4;

__device__ __forceinline__ unsigned short f2bf(float f) {
    union { float f; unsigned u; } v; v.f = f;
    unsigned r = v.u + 0x7fffu + ((v.u >> 16) & 1u);
    return (unsigned short)(r >> 16);
}

__device__ __forceinline__ void gl_lds16(const void* g, void* l) {
    __builtin_amdgcn_global_load_lds((const __attribute__((address_space(1))) unsigned int*)g,
                                     (__attribute__((address_space(3))) unsigned int*)l, 16, 0, 0);
}

// 64x64 f32->bf16 transpose tile. float4 loads, LDS [64][65] (2-way bank
// aliasing both phases = free), ushort4 packed stores (128B/16-lane row).
__device__ __forceinline__ void transpose64(const float* __restrict__ in,
                                            unsigned short* __restrict__ out,
                                            int R, int C, int bx, int by,
                                            int tid, float* tile) {
    int c0 = bx * 64, r0 = by * 64;
    int row = tid >> 4, c4 = tid & 15;
#pragma unroll
    for (int i = 0; i < 4; i++) {
        float4 v = *(const float4*)(in + (size_t)(r0 + row + i * 16) * C + c0 + c4 * 4);
        float* t = tile + (row + i * 16) * 65 + c4 * 4;
        t[0] = v.x; t[1] = v.y; t[2] = v.z; t[3] = v.w;
    }
    __syncthreads();
    int rq = tid & 15, ccb = tid >> 4;
#pragma unroll
    for (int i = 0; i < 4; i++) {
        int cc = ccb + i * 16;
        ushort4 o;
        o.x = f2bf(tile[(rq * 4 + 0) * 65 + cc]);
        o.y = f2bf(tile[(rq * 4 + 1) * 65 + cc]);
        o.z = f2bf(tile[(rq * 4 + 2) * 65 + cc]);
        o.w = f2bf(tile[(rq * 4 + 3) * 65 + cc]);
        *(ushort4*)(out + (size_t)(c0 + cc) * R + r0 + rq * 4) = o;
    }
}

// ---------------- prep_lite: featbf + W1T (the only gemm_bias inputs) ----------------
// grid: [0,192) feat conv (8 elems/thread) | [192,960) W1^T 64x64 tiles
__global__ __launch_bounds__(256) void prep_lite(const float* __restrict__ features,
                                                 const float* __restrict__ W1,
                                                 unsigned short* __restrict__ featbf,
                                                 unsigned short* __restrict__ W1T,
                                                 float* __restrict__ accum) {
    __shared__ float tile[64 * 65];
    int bid = blockIdx.x, tid = threadIdx.x;
    if (bid < 192) {
        if (bid == 0 && tid < 8) accum[tid] = 0.0f;
        int i = (bid * 256 + tid) * 8;
        float4 a = *(const float4*)(features + i);
        float4 b = *(const float4*)(features + i + 4);
        ushort4 o0, o1;
        o0.x = f2bf(a.x); o0.y = f2bf(a.y); o0.z = f2bf(a.z); o0.w = f2bf(a.w);
        o1.x = f2bf(b.x); o1.y = f2bf(b.y); o1.z = f2bf(b.z); o1.w = f2bf(b.w);
        *(ushort4*)(featbf + i) = o0;
        *(ushort4*)(featbf + i + 4) = o1;
        return;
    }
    // W1: 768x4096 -> W1T: 4096x768. 64 col-tiles x 12 row-tiles = 768 blocks
    int b = bid - 192;
    transpose64(W1, W1T, 768, 4096, b & 63, b >> 6, tid, tile);
}

// ---------------- mid_kernel: GEMM1+bias || compress stream || W2^T ----------------
// grid: [0,512) gemm_bias 64x64 tiles | [512,4608) compress | [4608,5632) W2^T
// GEMM blocks dispatch first (2/CU), compress streams alongside (no intra-
// dispatch dependency: compress/W2T outputs are consumed only by gemm_loss).
__global__ __launch_bounds__(256) void mid_kernel(const unsigned short* __restrict__ A,   // featbf 512x768
                                                  const unsigned short* __restrict__ BT,  // W1T 4096x768
                                                  const float* __restrict__ bias,         // b1
                                                  float* __restrict__ C,                  // xbuf 512x4096
                                                  const float* __restrict__ W2,
                                                  unsigned short* __restrict__ W2T,
                                                  const int* __restrict__ is_event,
                                                  const int* __restrict__ is_cens,
                                                  const float* __restrict__ ratio,
                                                  unsigned char* __restrict__ packed,
                                                  float* __restrict__ ratio_sel) {
    __shared__ union {
        struct { unsigned short lA[64 * 40]; unsigned short lB[64 * 40]; } g;
        float tile[64 * 65];
    } sm;
    int bid = blockIdx.x, tid = threadIdx.x;

    if (bid >= 4608) {
        // W2: 512x8192 -> W2T: 8192x512. 128 col-tiles x 8 row-tiles = 1024 blocks
        int b = bid - 4608;
        transpose64(W2, W2T, 512, 8192, b & 127, b >> 7, tid, sm.tile);
        return;
    }
    if (bid >= 512) {
        // ---- compress: is_event one-hot over T -> packed(u8: t|cen<<3) + ratio_sel ----
        const int NK = 8192;
        int gid = (bid - 512) * 256 + tid;         // [0, 1048576)
        int b = gid >> 11;
        int k0 = (gid & 2047) * 4;
        size_t base = (size_t)b * 8 * NK + k0;

        int4 c4 = *(const int4*)(is_cens + (size_t)b * NK + k0);
        int   tev[4]  = {0, 0, 0, 0};
        float rsel[4] = {0.f, 0.f, 0.f, 0.f};
#pragma unroll
        for (int t = 0; t < 8; t++) {
            int4   ev4 = *(const int4*)(is_event + base + (size_t)t * NK);
            float4 rt4 = *(const float4*)(ratio + base + (size_t)t * NK);
            int   vv[4] = {ev4.x, ev4.y, ev4.z, ev4.w};
            float rr[4] = {rt4.x, rt4.y, rt4.z, rt4.w};
#pragma unroll
            for (int j = 0; j < 4; j++) {
                bool e = vv[j] != 0;
                tev[j]  = e ? t : tev[j];
                rsel[j] = e ? rr[j] : rsel[j];
            }
        }
        int cc[4] = {c4.x, c4.y, c4.z, c4.w};
        uchar4 pk4;
        pk4.x = (unsigned char)(tev[0] | ((cc[0] != 0) << 3));
        pk4.y = (unsigned char)(tev[1] | ((cc[1] != 0) << 3));
        pk4.z = (unsigned char)(tev[2] | ((cc[2] != 0) << 3));
        pk4.w = (unsigned char)(tev[3] | ((cc[3] != 0) << 3));
        *(uchar4*)(packed + (size_t)gid * 4) = pk4;
        float4 rs4; rs4.x = rsel[0]; rs4.y = rsel[1]; rs4.z = rsel[2]; rs4.w = rsel[3];
        *(float4*)(ratio_sel + (size_t)gid * 4) = rs4;
        return;
    }

    // ---- gemm_bias: M=512, N=4096, K=768; 64x64 tile, 2x2 waves ----
    const int M = 512, N = 4096, K = 768;
    (void)M;
    int m0 = (bid & 7) * 64, n0 = (bid >> 3) * 64;
    int lane = tid & 63, wave = tid >> 6;
    int wm = wave >> 1, wn = wave & 1;
    int r = lane & 15, q = lane >> 4;

    f32x4 acc[2][2];
#pragma unroll
    for (int i = 0; i < 2; i++)
#pragma unroll
        for (int j = 0; j < 2; j++) acc[i][j] = (f32x4){0.f, 0.f, 0.f, 0.f};

    int ldrow = tid >> 2, ldc = (tid & 3) * 8;

    for (int kk = 0; kk < K; kk += 32) {
        uint4 av = *(const uint4*)(A + (size_t)(m0 + ldrow) * K + kk + ldc);
        uint4 bv = *(const uint4*)(BT + (size_t)(n0 + ldrow) * K + kk + ldc);
        __syncthreads();
        *(uint4*)(&sm.g.lA[ldrow * 40 + ldc]) = av;
        *(uint4*)(&sm.g.lB[ldrow * 40 + ldc]) = bv;
        __syncthreads();

        bf16x8 a0 = *(const bf16x8*)(&sm.g.lA[(wm * 32 + r) * 40 + q * 8]);
        bf16x8 a1 = *(const bf16x8*)(&sm.g.lA[(wm * 32 + 16 + r) * 40 + q * 8]);
        bf16x8 b0 = *(const bf16x8*)(&sm.g.lB[(wn * 32 + r) * 40 + q * 8]);
        bf16x8 b1 = *(const bf16x8*)(&sm.g.lB[(wn * 32 + 16 + r) * 40 + q * 8]);
        acc[0][0] = __builtin_amdgcn_mfma_f32_16x16x32_bf16(a0, b0, acc[0][0], 0, 0, 0);
        acc[0][1] = __builtin_amdgcn_mfma_f32_16x16x32_bf16(a0, b1, acc[0][1], 0, 0, 0);
        acc[1][0] = __builtin_amdgcn_mfma_f32_16x16x32_bf16(a1, b0, acc[1][0], 0, 0, 0);
        acc[1][1] = __builtin_amdgcn_mfma_f32_16x16x32_bf16(a1, b1, acc[1][1], 0, 0, 0);
    }

#pragma unroll
    for (int i = 0; i < 2; i++)
#pragma unroll
        for (int j = 0; j < 2; j++)
#pragma unroll
            for (int reg = 0; reg < 4; reg++) {
                int row = m0 + wm * 32 + i * 16 + q * 4 + reg;
                int col = n0 + wn * 32 + j * 16 + r;
                C[(size_t)row * N + col] = acc[i][j][reg] + bias[col];
            }
}

// ---------------- RMSNorm: x(4096x512) f32 -> xn(4096x512) bf16 ----------------
__global__ __launch_bounds__(256) void rms_kernel(const float* __restrict__ x,
                                                  const float* __restrict__ norm_w,
                                                  unsigned short* __restrict__ xn) {
    int m = blockIdx.x;
    int tid = threadIdx.x;
    const float* row = x + (size_t)m * 512;
    float v0 = row[tid];
    float v1 = row[tid + 256];
    float ss = v0 * v0 + v1 * v1;
#pragma unroll
    for (int o = 32; o > 0; o >>= 1) ss += __shfl_down(ss, o);
    __shared__ float rs[4];
    __shared__ float scale_sh;
    int lane = tid & 63, wave = tid >> 6;
    if (lane == 0) rs[wave] = ss;
    __syncthreads();
    if (tid == 0) {
        float tot = rs[0] + rs[1] + rs[2] + rs[3];
        scale_sh = 1.0f / sqrtf(tot * (1.0f / 512.0f) + 1e-6f);
    }
    __syncthreads();
    float s = scale_sh;
    xn[(size_t)m * 512 + tid] = f2bf(v0 * s * norm_w[tid]);
    xn[(size_t)m * 512 + tid + 256] = f2bf(v1 * s * norm_w[tid + 256]);
}

// ---------------- GEMM2 + softmax/cumsum/loss, fused (m97-style) ----------------
// M=4096, N=8192, K=512. BM=BN=128, BK=64, 256 threads = 4 waves (2x2).
__global__ __launch_bounds__(256) void gemm_loss(const unsigned short* __restrict__ A,
                                                 const unsigned short* __restrict__ BT,
                                                 const unsigned char* __restrict__ packed,
                                                 const float* __restrict__ ratio_sel,
                                                 float* __restrict__ accum) {
    const int K = 512, NK = 8192;
    __shared__ unsigned short lA[8 * 128 * 8];   // 16 KB: [kc][m][8]
    __shared__ unsigned short lB[8 * 128 * 8];   // 16 KB: [kc][n][8]
    __shared__ float lg[32 * 132];               // logits chunk, stride 132 (2-way max)
    __shared__ float rsum[4];

    int m0 = blockIdx.x * 128, n0 = blockIdx.y * 128;
    int tid = threadIdx.x;
    int lane = tid & 63, wave = tid >> 6;
    int wm = wave >> 1, wn = wave & 1;
    int r = lane & 15, q = lane >> 4;

    f32x4 acc[4][4];
#pragma unroll
    for (int i = 0; i < 4; i++)
#pragma unroll
        for (int j = 0; j < 4; j++) acc[i][j] = (f32x4){0.f, 0.f, 0.f, 0.f};

    for (int kk = 0; kk < K; kk += 64) {
        __syncthreads();   // previous iter's ds_reads complete
#pragma unroll
        for (int inst = 0; inst < 4; inst++) {
            int e = inst * 256 + tid;          // 0..1023
            int kc = e >> 7, m = e & 127;
            gl_lds16(A + (size_t)(m0 + m) * K + kk + kc * 8, (char*)lA + e * 16);
        }
#pragma unroll
        for (int inst = 0; inst < 4; inst++) {
            int e = inst * 256 + tid;
            int kc = e >> 7, n = e & 127;
            gl_lds16(BT + (size_t)(n0 + n) * K + kk + kc * 8, (char*)lB + e * 16);
        }
        __syncthreads();   // drains vmcnt -> staged data visible

#pragma unroll
        for (int ks = 0; ks < 2; ks++) {
            bf16x8 a[4], b[4];
#pragma unroll
            for (int i = 0; i < 4; i++)
                a[i] = *(const bf16x8*)((const char*)lA + (size_t)((ks * 4 + q) * 128 + wm * 64 + i * 16 + r) * 16);
#pragma unroll
            for (int j = 0; j < 4; j++)
                b[j] = *(const bf16x8*)((const char*)lB + (size_t)((ks * 4 + q) * 128 + wn * 64 + j * 16 + r) * 16);
#pragma unroll
            for (int i = 0; i < 4; i++)
#pragma unroll
                for (int j = 0; j < 4; j++)
                    acc[i][j] = __builtin_amdgcn_mfma_f32_16x16x32_bf16(a[i], b[j], acc[i][j], 0, 0, 0);
        }
    }

    // ---- epilogue: 4 chunks of 32 rows (4 b's x 8 t's) x 128 cols ----
    float lsum = 0.0f;
#pragma unroll
    for (int c = 0; c < 4; c++) {
        __syncthreads();   // previous chunk fully read (and k-loop ds_reads done)
        if (wm == (c >> 1)) {
#pragma unroll
            for (int di = 0; di < 2; di++)
#pragma unroll
                for (int j = 0; j < 4; j++)
#pragma unroll
                    for (int reg = 0; reg < 4; reg++) {
                        int lrow = di * 16 + q * 4 + reg;
                        int col = wn * 64 + j * 16 + r;
                        lg[lrow * 132 + col] = acc[(c & 1) * 2 + di][j][reg];
                    }
        }
        __syncthreads();

#pragma unroll
        for (int p = 0; p < 2; p++) {
            int idx = tid + p * 256;            // 512 (b,k) pairs per chunk
            int bl = idx >> 7, kl = idx & 127;  // bl in [0,4)
            int b = (m0 >> 3) + 4 * c + bl;
            int k = n0 + kl;
            size_t pidx = (size_t)b * NK + k;

            int pk = packed[pidx];
            float rsel = ratio_sel[pidx];
            int tev = pk & 7;
            bool cen = (pk & 8) != 0;

            float L[8];
#pragma unroll
            for (int t = 0; t < 8; t++) L[t] = lg[(bl * 8 + t) * 132 + kl];
            float mx = L[0];
#pragma unroll
            for (int t = 1; t < 8; t++) mx = fmaxf(mx, L[t]);
            float e[8], s = 0.0f;
#pragma unroll
            for (int t = 0; t < 8; t++) { e[t] = __expf(L[t] - mx); s += e[t]; }
            float inv = 1.0f / s;

            float cum = 0.0f, pte = 0.0f, ite = 0.0f;
#pragma unroll
            for (int t = 0; t < 8; t++) {
                float pt = e[t] * inv;
                float integ = 1.0f - cum;
                cum += pt;
                bool hit = (t == tev);
                pte = hit ? pt : pte;
                ite = hit ? integ : ite;
            }
            float ps  = fminf(fmaxf(pte, EPS), 1.0f - EPS);
            float is0 = fminf(fmaxf(ite, EPS), 1.0f - EPS);
            float isc = fminf(fmaxf(is0 - rsel * ps, EPS), 1.0f - EPS);
            float val = cen ? isc : ps;
            lsum += logf(val);
        }
    }

    // block reduction
#pragma unroll
    for (int o = 32; o > 0; o >>= 1) lsum += __shfl_down(lsum, o);
    if (lane == 0) rsum[wave] = lsum;
    __syncthreads();
    if (tid == 0) {
        atomicAdd(&accum[0], rsum[0] + rsum[1] + rsum[2] + rsum[3]);
    }
}

__global__ void finalize_kernel(const float* __restrict__ accum, float* __restrict__ out) {
    out[0] = -accum[0] / (NUM_MARKED * H_T);
}

extern "C" void kernel_launch(void* const* d_in, const int* in_sizes, int n_in,
                              void* d_out, int out_size, void* d_ws, size_t ws_size,
                              hipStream_t stream) {
    const float* features = (const float*)d_in[0]; // 512x768
    const float* W1       = (const float*)d_in[1]; // 768x4096
    const float* b1       = (const float*)d_in[2]; // 4096
    const float* norm_w   = (const float*)d_in[3]; // 512
    const float* W2       = (const float*)d_in[4]; // 512x8192
    /* b2 (d_in[5]) is softmax(axis=1)-invariant: skipped */
    const int* is_event   = (const int*)d_in[6];   // 512x8x8192 (bool as i32)
    const int* is_cens    = (const int*)d_in[7];   // 512x8192  (bool as i32)
    const float* ratio    = (const float*)d_in[8]; // 512x8x8192
    float* out = (float*)d_out;

    char* ws = (char*)d_ws;
    size_t off = 0;
    auto alloc = [&](size_t bytes) { void* p = ws + off; off = (off + bytes + 255) & ~(size_t)255; return p; };
    unsigned short* W1T    = (unsigned short*)alloc((size_t)4096 * 768 * 2);
    unsigned short* W2T    = (unsigned short*)alloc((size_t)8192 * 512 * 2);
    unsigned short* featbf = (unsigned short*)alloc((size_t)512 * 768 * 2);
    float*          xbuf   = (float*)alloc((size_t)512 * 4096 * 4);
    unsigned short* xn     = (unsigned short*)alloc((size_t)4096 * 512 * 2);
    unsigned char*  packed = (unsigned char*)alloc((size_t)512 * 8192);
    float*          rsel   = (float*)alloc((size_t)512 * 8192 * 4);
    float*          accum  = (float*)alloc(64);

    prep_lite<<<960, 256, 0, stream>>>(features, W1, featbf, W1T, accum);
    mid_kernel<<<5632, 256, 0, stream>>>(featbf, W1T, b1, xbuf, W2, W2T,
                                         is_event, is_cens, ratio, packed, rsel);
    rms_kernel<<<4096, 256, 0, stream>>>(xbuf, norm_w, xn);
    gemm_loss<<<dim3(4096 / 128, 8192 / 128), 256, 0, stream>>>(xn, W2T, packed, rsel, accum);
    finalize_kernel<<<1, 1, 0, stream>>>(accum, out);
}

// Round 3
// 413.835 us; speedup vs baseline: 1.0585x; 1.0112x over previous
//
#include <hip/hip_runtime.h>
#include <hip/hip_bf16.h>
#include <cstdint>
#include <cstddef>

#define EPS 1e-8f
#define H_T 2.0794415416798357f /* ln(8) */
#define NUM_MARKED 4194304.0f   /* B*K: is_event is exactly one-hot over T */

typedef __attribute__((ext_vector_type(8))) short bf16x8;
typedef __attribute__((ext_vector_type(4))) float f32x4;

__device__ __forceinline__ unsigned short f2bf(float f) {
    union { float f; unsigned u; } v; v.f = f;
    unsigned r = v.u + 0x7fffu + ((v.u >> 16) & 1u);
    return (unsigned short)(r >> 16);
}

__device__ __forceinline__ void gl_lds16(const void* g, void* l) {
    __builtin_amdgcn_global_load_lds((const __attribute__((address_space(1))) unsigned int*)g,
                                     (__attribute__((address_space(3))) unsigned int*)l, 16, 0, 0);
}

// 64x64 f32->bf16 transpose tile. float4 loads, LDS [64][65] (2-way bank
// aliasing both phases = free), ushort4 packed stores (128B/16-lane row).
__device__ __forceinline__ void transpose64(const float* __restrict__ in,
                                            unsigned short* __restrict__ out,
                                            int R, int C, int bx, int by,
                                            int tid, float* tile) {
    int c0 = bx * 64, r0 = by * 64;
    int row = tid >> 4, c4 = tid & 15;
#pragma unroll
    for (int i = 0; i < 4; i++) {
        float4 v = *(const float4*)(in + (size_t)(r0 + row + i * 16) * C + c0 + c4 * 4);
        float* t = tile + (row + i * 16) * 65 + c4 * 4;
        t[0] = v.x; t[1] = v.y; t[2] = v.z; t[3] = v.w;
    }
    __syncthreads();
    int rq = tid & 15, ccb = tid >> 4;
#pragma unroll
    for (int i = 0; i < 4; i++) {
        int cc = ccb + i * 16;
        ushort4 o;
        o.x = f2bf(tile[(rq * 4 + 0) * 65 + cc]);
        o.y = f2bf(tile[(rq * 4 + 1) * 65 + cc]);
        o.z = f2bf(tile[(rq * 4 + 2) * 65 + cc]);
        o.w = f2bf(tile[(rq * 4 + 3) * 65 + cc]);
        *(ushort4*)(out + (size_t)(c0 + cc) * R + r0 + rq * 4) = o;
    }
}

// ---------------- prep_lite: featbf + W1T (the only gemm_bias inputs) ----------------
// grid: [0,192) feat conv (8 elems/thread) | [192,960) W1^T 64x64 tiles
__global__ __launch_bounds__(256) void prep_lite(const float* __restrict__ features,
                                                 const float* __restrict__ W1,
                                                 unsigned short* __restrict__ featbf,
                                                 unsigned short* __restrict__ W1T,
                                                 float* __restrict__ accum) {
    __shared__ float tile[64 * 65];
    int bid = blockIdx.x, tid = threadIdx.x;
    if (bid < 192) {
        if (bid == 0 && tid < 8) accum[tid] = 0.0f;
        int i = (bid * 256 + tid) * 8;
        float4 a = *(const float4*)(features + i);
        float4 b = *(const float4*)(features + i + 4);
        ushort4 o0, o1;
        o0.x = f2bf(a.x); o0.y = f2bf(a.y); o0.z = f2bf(a.z); o0.w = f2bf(a.w);
        o1.x = f2bf(b.x); o1.y = f2bf(b.y); o1.z = f2bf(b.z); o1.w = f2bf(b.w);
        *(ushort4*)(featbf + i) = o0;
        *(ushort4*)(featbf + i + 4) = o1;
        return;
    }
    // W1: 768x4096 -> W1T: 4096x768. 64 col-tiles x 12 row-tiles = 768 blocks
    int b = bid - 192;
    transpose64(W1, W1T, 768, 4096, b & 63, b >> 6, tid, tile);
}

// ---------------- mid_kernel: GEMM1+bias || compress stream || W2^T ----------------
// grid: [0,512) gemm_bias 64x64 tiles | [512,4608) compress | [4608,5632) W2^T
__global__ __launch_bounds__(256) void mid_kernel(const unsigned short* __restrict__ A,   // featbf 512x768
                                                  const unsigned short* __restrict__ BT,  // W1T 4096x768
                                                  const float* __restrict__ bias,         // b1
                                                  float* __restrict__ C,                  // xbuf 512x4096
                                                  const float* __restrict__ W2,
                                                  unsigned short* __restrict__ W2T,
                                                  const int* __restrict__ is_event,
                                                  const int* __restrict__ is_cens,
                                                  const float* __restrict__ ratio,
                                                  unsigned char* __restrict__ packed,
                                                  float* __restrict__ ratio_sel) {
    __shared__ union {
        struct { unsigned short lA[64 * 40]; unsigned short lB[64 * 40]; } g;
        float tile[64 * 65];
    } sm;
    int bid = blockIdx.x, tid = threadIdx.x;

    if (bid >= 4608) {
        // W2: 512x8192 -> W2T: 8192x512. 128 col-tiles x 8 row-tiles = 1024 blocks
        int b = bid - 4608;
        transpose64(W2, W2T, 512, 8192, b & 127, b >> 7, tid, sm.tile);
        return;
    }
    if (bid >= 512) {
        // ---- compress: all 17 loads issued back-to-back (full MLP), then combine ----
        const int NK = 8192;
        int gid = (bid - 512) * 256 + tid;         // [0, 1048576)
        int b = gid >> 11;
        int k0 = (gid & 2047) * 4;
        size_t base = (size_t)b * 8 * NK + k0;

        int4 ev4[8]; float4 rt4[8];
#pragma unroll
        for (int t = 0; t < 8; t++) ev4[t] = *(const int4*)(is_event + base + (size_t)t * NK);
#pragma unroll
        for (int t = 0; t < 8; t++) rt4[t] = *(const float4*)(ratio + base + (size_t)t * NK);
        int4 c4 = *(const int4*)(is_cens + (size_t)b * NK + k0);

        int   tev[4]  = {0, 0, 0, 0};
        float rsel[4] = {0.f, 0.f, 0.f, 0.f};
#pragma unroll
        for (int t = 0; t < 8; t++) {
            int   vv[4] = {ev4[t].x, ev4[t].y, ev4[t].z, ev4[t].w};
            float rr[4] = {rt4[t].x, rt4[t].y, rt4[t].z, rt4[t].w};
#pragma unroll
            for (int j = 0; j < 4; j++) {
                bool e = vv[j] != 0;
                tev[j]  = e ? t : tev[j];
                rsel[j] = e ? rr[j] : rsel[j];
            }
        }
        int cc[4] = {c4.x, c4.y, c4.z, c4.w};
        uchar4 pk4;
        pk4.x = (unsigned char)(tev[0] | ((cc[0] != 0) << 3));
        pk4.y = (unsigned char)(tev[1] | ((cc[1] != 0) << 3));
        pk4.z = (unsigned char)(tev[2] | ((cc[2] != 0) << 3));
        pk4.w = (unsigned char)(tev[3] | ((cc[3] != 0) << 3));
        *(uchar4*)(packed + (size_t)gid * 4) = pk4;
        float4 rs4; rs4.x = rsel[0]; rs4.y = rsel[1]; rs4.z = rsel[2]; rs4.w = rsel[3];
        *(float4*)(ratio_sel + (size_t)gid * 4) = rs4;
        return;
    }

    // ---- gemm_bias: M=512, N=4096, K=768; 64x64 tile, 2x2 waves ----
    const int N = 4096, K = 768;
    int m0 = (bid & 7) * 64, n0 = (bid >> 3) * 64;
    int lane = tid & 63, wave = tid >> 6;
    int wm = wave >> 1, wn = wave & 1;
    int r = lane & 15, q = lane >> 4;

    f32x4 acc[2][2];
#pragma unroll
    for (int i = 0; i < 2; i++)
#pragma unroll
        for (int j = 0; j < 2; j++) acc[i][j] = (f32x4){0.f, 0.f, 0.f, 0.f};

    int ldrow = tid >> 2, ldc = (tid & 3) * 8;

    for (int kk = 0; kk < K; kk += 32) {
        uint4 av = *(const uint4*)(A + (size_t)(m0 + ldrow) * K + kk + ldc);
        uint4 bv = *(const uint4*)(BT + (size_t)(n0 + ldrow) * K + kk + ldc);
        __syncthreads();
        *(uint4*)(&sm.g.lA[ldrow * 40 + ldc]) = av;
        *(uint4*)(&sm.g.lB[ldrow * 40 + ldc]) = bv;
        __syncthreads();

        bf16x8 a0 = *(const bf16x8*)(&sm.g.lA[(wm * 32 + r) * 40 + q * 8]);
        bf16x8 a1 = *(const bf16x8*)(&sm.g.lA[(wm * 32 + 16 + r) * 40 + q * 8]);
        bf16x8 b0 = *(const bf16x8*)(&sm.g.lB[(wn * 32 + r) * 40 + q * 8]);
        bf16x8 b1 = *(const bf16x8*)(&sm.g.lB[(wn * 32 + 16 + r) * 40 + q * 8]);
        acc[0][0] = __builtin_amdgcn_mfma_f32_16x16x32_bf16(a0, b0, acc[0][0], 0, 0, 0);
        acc[0][1] = __builtin_amdgcn_mfma_f32_16x16x32_bf16(a0, b1, acc[0][1], 0, 0, 0);
        acc[1][0] = __builtin_amdgcn_mfma_f32_16x16x32_bf16(a1, b0, acc[1][0], 0, 0, 0);
        acc[1][1] = __builtin_amdgcn_mfma_f32_16x16x32_bf16(a1, b1, acc[1][1], 0, 0, 0);
    }

#pragma unroll
    for (int i = 0; i < 2; i++)
#pragma unroll
        for (int j = 0; j < 2; j++)
#pragma unroll
            for (int reg = 0; reg < 4; reg++) {
                int row = m0 + wm * 32 + i * 16 + q * 4 + reg;
                int col = n0 + wn * 32 + j * 16 + r;
                C[(size_t)row * N + col] = acc[i][j][reg] + bias[col];
            }
}

// ---------------- RMSNorm: x(4096x512) f32 -> xn(4096x512) bf16 ----------------
__global__ __launch_bounds__(256) void rms_kernel(const float* __restrict__ x,
                                                  const float* __restrict__ norm_w,
                                                  unsigned short* __restrict__ xn) {
    int m = blockIdx.x;
    int tid = threadIdx.x;
    const float* row = x + (size_t)m * 512;
    float v0 = row[tid];
    float v1 = row[tid + 256];
    float ss = v0 * v0 + v1 * v1;
#pragma unroll
    for (int o = 32; o > 0; o >>= 1) ss += __shfl_down(ss, o);
    __shared__ float rs[4];
    __shared__ float scale_sh;
    int lane = tid & 63, wave = tid >> 6;
    if (lane == 0) rs[wave] = ss;
    __syncthreads();
    if (tid == 0) {
        float tot = rs[0] + rs[1] + rs[2] + rs[3];
        scale_sh = 1.0f / sqrtf(tot * (1.0f / 512.0f) + 1e-6f);
    }
    __syncthreads();
    float s = scale_sh;
    xn[(size_t)m * 512 + tid] = f2bf(v0 * s * norm_w[tid]);
    xn[(size_t)m * 512 + tid + 256] = f2bf(v1 * s * norm_w[tid + 256]);
}

// ---------------- GEMM2 + softmax/cumsum/loss, fused ----------------
// M=4096, N=8192, K=512. BM=BN=128, BK=64, 256 threads = 4 waves (2x2).
// Epilogue is fully in-register: MFMA C-layout puts one (b,k) pair's 8
// t-logits in TWO lanes (lane ^ 16), 4 regs each (row=q*4+reg, t=row&7,
// b_local=q>>1). Softmax/cumsum/select = local 4-reg ops + one
// __shfl_xor(16) per reduction. No lg LDS buffer, no epilogue barriers
// (R2 profile: 4-chunk LDS epilogue + 50KB block -> 3 blocks/CU,
// MfmaUtil 13%, occupancy 20%).
__global__ __launch_bounds__(256) void gemm_loss(const unsigned short* __restrict__ A,
                                                 const unsigned short* __restrict__ BT,
                                                 const unsigned char* __restrict__ packed,
                                                 const float* __restrict__ ratio_sel,
                                                 float* __restrict__ accum) {
    const int K = 512, NK = 8192;
    __shared__ unsigned short lA[8 * 128 * 8];   // 16 KB: [kc][m][8]
    __shared__ unsigned short lB[8 * 128 * 8];   // 16 KB: [kc][n][8]
    __shared__ float rsum[4];

    int m0 = blockIdx.x * 128, n0 = blockIdx.y * 128;
    int tid = threadIdx.x;
    int lane = tid & 63, wave = tid >> 6;
    int wm = wave >> 1, wn = wave & 1;
    int r = lane & 15, q = lane >> 4;

    f32x4 acc[4][4];
#pragma unroll
    for (int i = 0; i < 4; i++)
#pragma unroll
        for (int j = 0; j < 4; j++) acc[i][j] = (f32x4){0.f, 0.f, 0.f, 0.f};

    for (int kk = 0; kk < K; kk += 64) {
        __syncthreads();   // previous iter's ds_reads complete
#pragma unroll
        for (int inst = 0; inst < 4; inst++) {
            int e = inst * 256 + tid;          // 0..1023
            int kc = e >> 7, m = e & 127;
            gl_lds16(A + (size_t)(m0 + m) * K + kk + kc * 8, (char*)lA + e * 16);
        }
#pragma unroll
        for (int inst = 0; inst < 4; inst++) {
            int e = inst * 256 + tid;
            int kc = e >> 7, n = e & 127;
            gl_lds16(BT + (size_t)(n0 + n) * K + kk + kc * 8, (char*)lB + e * 16);
        }
        __syncthreads();   // drains vmcnt -> staged data visible

#pragma unroll
        for (int ks = 0; ks < 2; ks++) {
            bf16x8 a[4], b[4];
#pragma unroll
            for (int i = 0; i < 4; i++)
                a[i] = *(const bf16x8*)((const char*)lA + (size_t)((ks * 4 + q) * 128 + wm * 64 + i * 16 + r) * 16);
#pragma unroll
            for (int j = 0; j < 4; j++)
                b[j] = *(const bf16x8*)((const char*)lB + (size_t)((ks * 4 + q) * 128 + wn * 64 + j * 16 + r) * 16);
#pragma unroll
            for (int i = 0; i < 4; i++)
#pragma unroll
                for (int j = 0; j < 4; j++)
                    acc[i][j] = __builtin_amdgcn_mfma_f32_16x16x32_bf16(a[i], b[j], acc[i][j], 0, 0, 0);
        }
    }

    // ---- in-register epilogue ----
    int qpar = q & 1, qb = q >> 1;
    int base_b = (m0 + wm * 64) >> 3;
    int kbase = n0 + wn * 64 + r;

    // hoist all packed/rsel loads (L2/L3-hot, one latency for all 32)
    int pk[4][4]; float rsl[4][4];
#pragma unroll
    for (int i = 0; i < 4; i++) {
        int b = base_b + i * 2 + qb;
#pragma unroll
        for (int j = 0; j < 4; j++) {
            size_t pidx = (size_t)b * NK + kbase + j * 16;
            pk[i][j] = packed[pidx];
            rsl[i][j] = ratio_sel[pidx];
        }
    }

    float lsum = 0.0f;
#pragma unroll
    for (int i = 0; i < 4; i++) {
#pragma unroll
        for (int j = 0; j < 4; j++) {
            f32x4 v = acc[i][j];
            float mx_loc = fmaxf(fmaxf(v[0], v[1]), fmaxf(v[2], v[3]));
            float mx = fmaxf(mx_loc, __shfl_xor(mx_loc, 16));
            float e0 = __expf(v[0] - mx), e1 = __expf(v[1] - mx);
            float e2 = __expf(v[2] - mx), e3 = __expf(v[3] - mx);
            float sl = e0 + e1 + e2 + e3;
            float so = __shfl_xor(sl, 16);
            float inv = 1.0f / (sl + so);
            // prefix sums (cum BEFORE each local t)
            float c1 = e0, c2 = e0 + e1, c3 = e0 + e1 + e2;
            float off = qpar ? so : 0.0f;   // partner holds t=0..3 when we hold 4..7

            int tev = pk[i][j] & 7;
            int tloc = tev - qpar * 4;
            bool mine = (tev >> 2) == qpar;
            float pe = (tloc == 0) ? e0 : (tloc == 1) ? e1 : (tloc == 2) ? e2 : e3;
            float ce = (tloc == 0) ? 0.0f : (tloc == 1) ? c1 : (tloc == 2) ? c2 : c3;
            float pte_loc = mine ? pe * inv : 0.0f;
            float ite_loc = mine ? 1.0f - (off + ce) * inv : 0.0f;
            float pte = pte_loc + __shfl_xor(pte_loc, 16);
            float ite = ite_loc + __shfl_xor(ite_loc, 16);

            float ps  = fminf(fmaxf(pte, EPS), 1.0f - EPS);
            float is0 = fminf(fmaxf(ite, EPS), 1.0f - EPS);
            float isc = fminf(fmaxf(is0 - rsl[i][j] * ps, EPS), 1.0f - EPS);
            float val = (pk[i][j] & 8) ? isc : ps;
            lsum += (qpar == 0) ? logf(val) : 0.0f;
        }
    }

    // block reduction
#pragma unroll
    for (int o = 32; o > 0; o >>= 1) lsum += __shfl_down(lsum, o);
    if (lane == 0) rsum[wave] = lsum;
    __syncthreads();
    if (tid == 0) {
        atomicAdd(&accum[0], rsum[0] + rsum[1] + rsum[2] + rsum[3]);
    }
}

__global__ void finalize_kernel(const float* __restrict__ accum, float* __restrict__ out) {
    out[0] = -accum[0] / (NUM_MARKED * H_T);
}

extern "C" void kernel_launch(void* const* d_in, const int* in_sizes, int n_in,
                              void* d_out, int out_size, void* d_ws, size_t ws_size,
                              hipStream_t stream) {
    const float* features = (const float*)d_in[0]; // 512x768
    const float* W1       = (const float*)d_in[1]; // 768x4096
    const float* b1       = (const float*)d_in[2]; // 4096
    const float* norm_w   = (const float*)d_in[3]; // 512
    const float* W2       = (const float*)d_in[4]; // 512x8192
    /* b2 (d_in[5]) is softmax(axis=1)-invariant: skipped */
    const int* is_event   = (const int*)d_in[6];   // 512x8x8192 (bool as i32)
    const int* is_cens    = (const int*)d_in[7];   // 512x8192  (bool as i32)
    const float* ratio    = (const float*)d_in[8]; // 512x8x8192
    float* out = (float*)d_out;

    char* ws = (char*)d_ws;
    size_t off = 0;
    auto alloc = [&](size_t bytes) { void* p = ws + off; off = (off + bytes + 255) & ~(size_t)255; return p; };
    unsigned short* W1T    = (unsigned short*)alloc((size_t)4096 * 768 * 2);
    unsigned short* W2T    = (unsigned short*)alloc((size_t)8192 * 512 * 2);
    unsigned short* featbf = (unsigned short*)alloc((size_t)512 * 768 * 2);
    float*          xbuf   = (float*)alloc((size_t)512 * 4096 * 4);
    unsigned short* xn     = (unsigned short*)alloc((size_t)4096 * 512 * 2);
    unsigned char*  packed = (unsigned char*)alloc((size_t)512 * 8192);
    float*          rsel   = (float*)alloc((size_t)512 * 8192 * 4);
    float*          accum  = (float*)alloc(64);

    prep_lite<<<960, 256, 0, stream>>>(features, W1, featbf, W1T, accum);
    mid_kernel<<<5632, 256, 0, stream>>>(featbf, W1T, b1, xbuf, W2, W2T,
                                         is_event, is_cens, ratio, packed, rsel);
    rms_kernel<<<4096, 256, 0, stream>>>(xbuf, norm_w, xn);
    gemm_loss<<<dim3(4096 / 128, 8192 / 128), 256, 0, stream>>>(xn, W2T, packed, rsel, accum);
    finalize_kernel<<<1, 1, 0, stream>>>(accum, out);
}